// Round 1
// baseline (5711.075 us; speedup 1.0000x reference)
//
#include <hip/hip_runtime.h>
#include <math.h>

#define BN   32768
#define MAXD 60
#define HDIM 256
#define TR   16

// ---------------- helpers ----------------

// Batched per-row LayerNorm statistics across the 256 threads of the block.
// acc[r] is the value this thread (column j) holds for row r.
__device__ __forceinline__ void row_reduce(float* red, const float acc[TR],
                                           float m[TR], float rs[TR], int j) {
  const int lane = j & 63, wv = j >> 6;
  __syncthreads();  // protect `red` reuse from a previous reduction
  #pragma unroll
  for (int r = 0; r < TR; ++r) {
    float s = acc[r], q = acc[r] * acc[r];
    #pragma unroll
    for (int o = 32; o; o >>= 1) { s += __shfl_xor(s, o); q += __shfl_xor(q, o); }
    if (lane == 0) { red[r * 8 + wv * 2] = s; red[r * 8 + wv * 2 + 1] = q; }
  }
  __syncthreads();
  #pragma unroll
  for (int r = 0; r < TR; ++r) {
    float s = red[r * 8 + 0] + red[r * 8 + 2] + red[r * 8 + 4] + red[r * 8 + 6];
    float q = red[r * 8 + 1] + red[r * 8 + 3] + red[r * 8 + 5] + red[r * 8 + 7];
    float mean = s * (1.0f / HDIM);
    float var  = q * (1.0f / HDIM) - mean * mean;
    m[r]  = mean;
    rs[r] = rsqrtf(var + 1e-5f);
  }
}

// acc[r] += sum_k x[r][k] * W[k][j], x staged in LDS (rows stride ST floats).
template <int KD, int ST>
__device__ __forceinline__ void matvec_l(const float* __restrict__ W,
                                         const float* zz, float acc[TR], int j) {
  #pragma unroll 2
  for (int k = 0; k < KD; k += 4) {
    const float w0 = W[(k + 0) * HDIM + j];
    const float w1 = W[(k + 1) * HDIM + j];
    const float w2 = W[(k + 2) * HDIM + j];
    const float w3 = W[(k + 3) * HDIM + j];
    #pragma unroll
    for (int r = 0; r < TR; ++r) {
      const float4 x = *(const float4*)(zz + r * ST + k);
      acc[r] = fmaf(x.w, w3, fmaf(x.z, w2, fmaf(x.y, w1, fmaf(x.x, w0, acc[r]))));
    }
  }
}

// ---------------- bucketing ----------------

__global__ __launch_bounds__(256) void bucket_kernel(
    const int* __restrict__ atid, const int* __restrict__ itid,
    int* cnts, int* idxA, int* idxI, int* idxC) {
  __shared__ int lcnt[15], lbase[15];
  const int tid = threadIdx.x;
  const int r = blockIdx.x * 256 + tid;
  if (tid < 15) lcnt[tid] = 0;
  __syncthreads();
  const int a = atid[r], i = itid[r];
  const int c = a * 3 + i;
  const int la = atomicAdd(&lcnt[a], 1);
  const int li = atomicAdd(&lcnt[3 + i], 1);
  const int lc = atomicAdd(&lcnt[6 + c], 1);
  __syncthreads();
  if (tid < 15) lbase[tid] = atomicAdd(&cnts[tid], lcnt[tid]);
  __syncthreads();
  idxA[a * BN + lbase[a] + la] = r;
  idxI[i * BN + lbase[3 + i] + li] = r;
  idxC[c * BN + lbase[6 + c] + lc] = r;
}

// ---------------- encoder ----------------

__global__ __launch_bounds__(256) void enc_kernel(
    const float* __restrict__ af, const float* __restrict__ itf,
    const int* __restrict__ idxA, const int* __restrict__ idxI,
    const int* __restrict__ cnts,
    const float* __restrict__ W1, const float* __restrict__ b1,
    const float* __restrict__ g1, const float* __restrict__ be1,
    const float* __restrict__ W2, const float* __restrict__ b2,
    const float* __restrict__ g2, const float* __restrict__ be2,
    float* __restrict__ ha, float* __restrict__ hi) {
  const int t = blockIdx.y, ent = blockIdx.z;
  const int cnt = cnts[ent * 3 + t];
  const int base = blockIdx.x * TR;
  if (base >= cnt) return;
  const int nr = (cnt - base < TR) ? (cnt - base) : TR;
  const int j = threadIdx.x;
  const float* feats = ent ? itf : af;
  const int* idx = (ent ? idxI : idxA) + t * BN;
  float* hout = ent ? hi : ha;

  __shared__ __align__(16) float xl[TR * 64];
  __shared__ __align__(16) float z[TR * HDIM];
  __shared__ float red[TR * 8];

  int rows[TR];
  #pragma unroll
  for (int r = 0; r < TR; ++r) {
    int rr = base + r; if (rr > cnt - 1) rr = cnt - 1;
    rows[r] = idx[rr];
  }
  if (j < 64) {
    #pragma unroll
    for (int r = 0; r < TR; ++r)
      xl[r * 64 + j] = (j < MAXD) ? feats[(size_t)rows[r] * MAXD + j] : 0.0f;
  }
  __syncthreads();

  float acc[TR];
  const float bj = b1[t * HDIM + j];
  #pragma unroll
  for (int r = 0; r < TR; ++r) acc[r] = bj;
  matvec_l<MAXD, 64>(W1 + (size_t)t * MAXD * HDIM, xl, acc, j);

  float m[TR], rs[TR];
  row_reduce(red, acc, m, rs, j);
  const float g1j = g1[t * HDIM + j], be1j = be1[t * HDIM + j];
  #pragma unroll
  for (int r = 0; r < TR; ++r)
    z[r * HDIM + j] = fmaxf((acc[r] - m[r]) * rs[r] * g1j + be1j, 0.0f);
  __syncthreads();

  const float b2j = b2[t * HDIM + j];
  #pragma unroll
  for (int r = 0; r < TR; ++r) acc[r] = b2j;
  matvec_l<HDIM, HDIM>(W2 + (size_t)t * HDIM * HDIM, z, acc, j);

  row_reduce(red, acc, m, rs, j);
  const float g2j = g2[t * HDIM + j], be2j = be2[t * HDIM + j];
  #pragma unroll
  for (int r = 0; r < TR; ++r)
    if (r < nr)
      hout[(size_t)rows[r] * HDIM + j] =
          fmaxf((acc[r] - m[r]) * rs[r] * g2j + be2j, 0.0f);
}

// ---------------- HGT hop ----------------

__device__ __forceinline__ void hgt_dir(
    const float* __restrict__ Wq, const float* __restrict__ Wk,
    const float* __restrict__ Wv, const float* __restrict__ Wo,
    const float* __restrict__ gg, const float* __restrict__ bb,
    const float* dstl, const float* srcl, float* msg, float* red, int j,
    float res[TR]) {
  float q[TR], kk[TR];
  #pragma unroll
  for (int r = 0; r < TR; ++r) { q[r] = 0.0f; kk[r] = 0.0f; }
  matvec_l<HDIM, HDIM>(Wq, dstl, q, j);
  matvec_l<HDIM, HDIM>(Wk, srcl, kk, j);

  float attn[TR];
  #pragma unroll
  for (int r = 0; r < TR; ++r) {
    float p = q[r] * kk[r];
    #pragma unroll
    for (int o = 32; o; o >>= 1) p += __shfl_xor(p, o);  // head == wave (HD=64)
    attn[r] = 1.0f / (1.0f + expf(-p * 0.125f));         // sigmoid(s / sqrt(64))
  }

  #pragma unroll
  for (int r = 0; r < TR; ++r) q[r] = 0.0f;
  matvec_l<HDIM, HDIM>(Wv, srcl, q, j);  // v into q regs

  __syncthreads();  // previous users of msg done
  #pragma unroll
  for (int r = 0; r < TR; ++r) msg[r * HDIM + j] = attn[r] * q[r];
  __syncthreads();

  float o[TR];
  #pragma unroll
  for (int r = 0; r < TR; ++r) o[r] = 0.0f;
  matvec_l<HDIM, HDIM>(Wo, msg, o, j);

  float u[TR], m[TR], rs[TR];
  #pragma unroll
  for (int r = 0; r < TR; ++r) u[r] = dstl[r * HDIM + j] + o[r];
  row_reduce(red, u, m, rs, j);
  const float gj = gg[j], bj = bb[j];
  #pragma unroll
  for (int r = 0; r < TR; ++r) res[r] = (u[r] - m[r]) * rs[r] * gj + bj;
}

__global__ __launch_bounds__(256) void hop_kernel(
    const float* __restrict__ Wk, const float* __restrict__ Wq,
    const float* __restrict__ Wv, const float* __restrict__ Wout,
    const float* __restrict__ g, const float* __restrict__ b,
    const int* __restrict__ idxC, const int* __restrict__ cnts,
    float* __restrict__ ha, float* __restrict__ hi) {
  const int c = blockIdx.y, a = c / 3, i = c % 3;
  const int cnt = cnts[6 + c];
  const int base = blockIdx.x * TR;
  if (base >= cnt) return;
  const int nr = (cnt - base < TR) ? (cnt - base) : TR;
  const int j = threadIdx.x;

  __shared__ __align__(16) float xa[TR * HDIM];
  __shared__ __align__(16) float xi[TR * HDIM];
  __shared__ __align__(16) float msg[TR * HDIM];
  __shared__ float red[TR * 8];

  int rows[TR];
  #pragma unroll
  for (int r = 0; r < TR; ++r) {
    int rr = base + r; if (rr > cnt - 1) rr = cnt - 1;
    rows[r] = idxC[c * BN + rr];
  }
  #pragma unroll
  for (int r = 0; r < TR; ++r) {
    xa[r * HDIM + j] = ha[(size_t)rows[r] * HDIM + j];
    xi[r * HDIM + j] = hi[(size_t)rows[r] * HDIM + j];
  }
  __syncthreads();

  const int e1 = i * 3 + a;  // item -> anchor edge, updates ha, dt = a
  const int e2 = a * 3 + i;  // anchor -> item edge, updates hi, dt = i
  float res1[TR], res2[TR];
  hgt_dir(Wq + (size_t)e1 * HDIM * HDIM, Wk + (size_t)e1 * HDIM * HDIM,
          Wv + (size_t)e1 * HDIM * HDIM, Wout + (size_t)a * HDIM * HDIM,
          g + a * HDIM, b + a * HDIM, xa, xi, msg, red, j, res1);
  hgt_dir(Wq + (size_t)e2 * HDIM * HDIM, Wk + (size_t)e2 * HDIM * HDIM,
          Wv + (size_t)e2 * HDIM * HDIM, Wout + (size_t)i * HDIM * HDIM,
          g + i * HDIM, b + i * HDIM, xi, xa, msg, red, j, res2);

  #pragma unroll
  for (int r = 0; r < TR; ++r)
    if (r < nr) {
      ha[(size_t)rows[r] * HDIM + j] = res1[r];
      hi[(size_t)rows[r] * HDIM + j] = res2[r];
    }
}

// ---------------- output projection + LN + l2norm ----------------

__global__ __launch_bounds__(256) void out_kernel(
    const float* __restrict__ W, const float* __restrict__ bb,
    const float* __restrict__ g, const float* __restrict__ be,
    float* __restrict__ out) {
  const int ent = blockIdx.y;
  const int base = blockIdx.x * TR;
  const int j = threadIdx.x;
  float* hsrc = out + (size_t)ent * BN * HDIM;

  __shared__ __align__(16) float xl[TR * HDIM];
  __shared__ float red[TR * 8];

  #pragma unroll
  for (int r = 0; r < TR; ++r)
    xl[r * HDIM + j] = hsrc[(size_t)(base + r) * HDIM + j];
  __syncthreads();

  float acc[TR];
  const float bj = bb[j];
  #pragma unroll
  for (int r = 0; r < TR; ++r) acc[r] = bj;
  matvec_l<HDIM, HDIM>(W, xl, acc, j);

  float m[TR], rs[TR];
  row_reduce(red, acc, m, rs, j);
  const float gj = g[j], bej = be[j];
  float y[TR];
  #pragma unroll
  for (int r = 0; r < TR; ++r) y[r] = (acc[r] - m[r]) * rs[r] * gj + bej;

  // l2 normalize
  const int lane = j & 63, wv = j >> 6;
  __syncthreads();
  #pragma unroll
  for (int r = 0; r < TR; ++r) {
    float p = y[r] * y[r];
    #pragma unroll
    for (int o = 32; o; o >>= 1) p += __shfl_xor(p, o);
    if (lane == 0) red[r * 4 + wv] = p;
  }
  __syncthreads();
  #pragma unroll
  for (int r = 0; r < TR; ++r) {
    float ss = red[r * 4] + red[r * 4 + 1] + red[r * 4 + 2] + red[r * 4 + 3];
    float inv = 1.0f / fmaxf(sqrtf(ss), 1e-12f);
    hsrc[(size_t)(base + r) * HDIM + j] = y[r] * inv;
  }
}

// ---------------- launch ----------------

extern "C" void kernel_launch(void* const* d_in, const int* in_sizes, int n_in,
                              void* d_out, int out_size, void* d_ws,
                              size_t ws_size, hipStream_t stream) {
  const float* af   = (const float*)d_in[0];
  const float* itf  = (const float*)d_in[1];
  const int*   atid = (const int*)d_in[2];
  const int*   itid = (const int*)d_in[3];
  const float* eW1  = (const float*)d_in[4];
  const float* eb1  = (const float*)d_in[5];
  const float* eg1  = (const float*)d_in[6];
  const float* ebe1 = (const float*)d_in[7];
  const float* eW2  = (const float*)d_in[8];
  const float* eb2  = (const float*)d_in[9];
  const float* eg2  = (const float*)d_in[10];
  const float* ebe2 = (const float*)d_in[11];
  const float* hWk  = (const float*)d_in[12];
  const float* hWq  = (const float*)d_in[13];
  const float* hWv  = (const float*)d_in[14];
  const float* hWo  = (const float*)d_in[15];
  const float* hg   = (const float*)d_in[16];
  const float* hb   = (const float*)d_in[17];
  const float* oW   = (const float*)d_in[18];
  const float* ob   = (const float*)d_in[19];
  const float* og   = (const float*)d_in[20];
  const float* obe  = (const float*)d_in[21];

  float* out = (float*)d_out;
  // ha/hi live inside d_out (exactly 2*BN*HDIM floats); final kernel
  // normalizes them in place. d_ws only holds bucket metadata (~2 MB).
  float* ha = out;
  float* hi = out + (size_t)BN * HDIM;

  int* cnts = (int*)d_ws;       // [15] : anchor-type 0..2, item-type 3..5, combo 6..14
  int* idxA = cnts + 16;        // [3][BN]
  int* idxI = idxA + 3 * BN;    // [3][BN]
  int* idxC = idxI + 3 * BN;    // [9][BN]

  hipMemsetAsync(cnts, 0, 16 * sizeof(int), stream);
  bucket_kernel<<<BN / 256, 256, 0, stream>>>(atid, itid, cnts, idxA, idxI, idxC);

  dim3 genc((BN + TR - 1) / TR, 3, 2);
  enc_kernel<<<genc, 256, 0, stream>>>(af, itf, idxA, idxI, cnts,
                                       eW1, eb1, eg1, ebe1, eW2, eb2, eg2, ebe2,
                                       ha, hi);

  for (int L = 0; L < 2; ++L) {
    hop_kernel<<<dim3((BN + TR - 1) / TR, 9), 256, 0, stream>>>(
        hWk + (size_t)L * 9 * HDIM * HDIM, hWq + (size_t)L * 9 * HDIM * HDIM,
        hWv + (size_t)L * 9 * HDIM * HDIM, hWo + (size_t)L * 3 * HDIM * HDIM,
        hg + L * 3 * HDIM, hb + L * 3 * HDIM, idxC, cnts, ha, hi);
  }

  out_kernel<<<dim3(BN / TR, 2), 256, 0, stream>>>(oW, ob, og, obe, out);
}

// Round 2
// 954.300 us; speedup vs baseline: 5.9846x; 5.9846x over previous
//
#include <hip/hip_runtime.h>
#include <math.h>

#define BN   32768
#define MAXD 60
#define HDIM 256
#define TR   16

typedef __attribute__((ext_vector_type(4))) float f32x4;
typedef __attribute__((ext_vector_type(8))) short bf16x8;

__device__ __forceinline__ unsigned short f2bf(float f) {
  union { float f; unsigned u; } v; v.f = f;
  unsigned r = v.u + 0x7FFF + ((v.u >> 16) & 1);
  return (unsigned short)(r >> 16);
}

// ---------------- helpers (fp32 path, also used by enc/out) ----------------

__device__ __forceinline__ void row_reduce(float* red, const float acc[TR],
                                           float m[TR], float rs[TR], int j) {
  const int lane = j & 63, wv = j >> 6;
  __syncthreads();
  #pragma unroll
  for (int r = 0; r < TR; ++r) {
    float s = acc[r], q = acc[r] * acc[r];
    #pragma unroll
    for (int o = 32; o; o >>= 1) { s += __shfl_xor(s, o); q += __shfl_xor(q, o); }
    if (lane == 0) { red[r * 8 + wv * 2] = s; red[r * 8 + wv * 2 + 1] = q; }
  }
  __syncthreads();
  #pragma unroll
  for (int r = 0; r < TR; ++r) {
    float s = red[r * 8 + 0] + red[r * 8 + 2] + red[r * 8 + 4] + red[r * 8 + 6];
    float q = red[r * 8 + 1] + red[r * 8 + 3] + red[r * 8 + 5] + red[r * 8 + 7];
    float mean = s * (1.0f / HDIM);
    float var  = q * (1.0f / HDIM) - mean * mean;
    m[r]  = mean;
    rs[r] = rsqrtf(var + 1e-5f);
  }
}

template <int KD, int ST>
__device__ __forceinline__ void matvec_l(const float* __restrict__ W,
                                         const float* zz, float acc[TR], int j) {
  #pragma unroll 2
  for (int k = 0; k < KD; k += 4) {
    const float w0 = W[(k + 0) * HDIM + j];
    const float w1 = W[(k + 1) * HDIM + j];
    const float w2 = W[(k + 2) * HDIM + j];
    const float w3 = W[(k + 3) * HDIM + j];
    #pragma unroll
    for (int r = 0; r < TR; ++r) {
      const float4 x = *(const float4*)(zz + r * ST + k);
      acc[r] = fmaf(x.w, w3, fmaf(x.z, w2, fmaf(x.y, w1, fmaf(x.x, w0, acc[r]))));
    }
  }
}

// ---------------- bucketing ----------------

__global__ __launch_bounds__(256) void bucket_kernel(
    const int* __restrict__ atid, const int* __restrict__ itid,
    int* cnts, int* idxA, int* idxI, int* idxC) {
  __shared__ int lcnt[15], lbase[15];
  const int tid = threadIdx.x;
  const int r = blockIdx.x * 256 + tid;
  if (tid < 15) lcnt[tid] = 0;
  __syncthreads();
  const int a = atid[r], i = itid[r];
  const int c = a * 3 + i;
  const int la = atomicAdd(&lcnt[a], 1);
  const int li = atomicAdd(&lcnt[3 + i], 1);
  const int lc = atomicAdd(&lcnt[6 + c], 1);
  __syncthreads();
  if (tid < 15) lbase[tid] = atomicAdd(&cnts[tid], lcnt[tid]);
  __syncthreads();
  idxA[a * BN + lbase[a] + la] = r;
  idxI[i * BN + lbase[3 + i] + li] = r;
  idxC[c * BN + lbase[6 + c] + lc] = r;
}

// ---------------- weight convert: fp32 [k][n] -> bf16 transposed [n][k] ----

__global__ __launch_bounds__(256) void wconv_kernel(
    const float* __restrict__ Wk, const float* __restrict__ Wq,
    const float* __restrict__ Wv, const float* __restrict__ Wo,
    unsigned short* __restrict__ bWk, unsigned short* __restrict__ bWq,
    unsigned short* __restrict__ bWv, unsigned short* __restrict__ bWo) {
  const int idx = blockIdx.x * 256 + threadIdx.x;  // over 60*65536
  const int m = idx >> 16;
  const int e = idx & 65535;
  const int n = e >> 8, k = e & 255;
  const float* src; unsigned short* dst; int ml;
  if (m < 18)      { src = Wk; dst = bWk; ml = m; }
  else if (m < 36) { src = Wq; dst = bWq; ml = m - 18; }
  else if (m < 54) { src = Wv; dst = bWv; ml = m - 36; }
  else             { src = Wo; dst = bWo; ml = m - 54; }
  dst[(size_t)ml * 65536 + e] = f2bf(src[(size_t)ml * 65536 + k * 256 + n]);
}

// ---------------- encoder (fp32, unchanged) ----------------

__global__ __launch_bounds__(256) void enc_kernel(
    const float* __restrict__ af, const float* __restrict__ itf,
    const int* __restrict__ idxA, const int* __restrict__ idxI,
    const int* __restrict__ cnts,
    const float* __restrict__ W1, const float* __restrict__ b1,
    const float* __restrict__ g1, const float* __restrict__ be1,
    const float* __restrict__ W2, const float* __restrict__ b2,
    const float* __restrict__ g2, const float* __restrict__ be2,
    float* __restrict__ ha, float* __restrict__ hi) {
  const int t = blockIdx.y, ent = blockIdx.z;
  const int cnt = cnts[ent * 3 + t];
  const int base = blockIdx.x * TR;
  if (base >= cnt) return;
  const int nr = (cnt - base < TR) ? (cnt - base) : TR;
  const int j = threadIdx.x;
  const float* feats = ent ? itf : af;
  const int* idx = (ent ? idxI : idxA) + t * BN;
  float* hout = ent ? hi : ha;

  __shared__ __align__(16) float xl[TR * 64];
  __shared__ __align__(16) float z[TR * HDIM];
  __shared__ float red[TR * 8];

  int rows[TR];
  #pragma unroll
  for (int r = 0; r < TR; ++r) {
    int rr = base + r; if (rr > cnt - 1) rr = cnt - 1;
    rows[r] = idx[rr];
  }
  if (j < 64) {
    #pragma unroll
    for (int r = 0; r < TR; ++r)
      xl[r * 64 + j] = (j < MAXD) ? feats[(size_t)rows[r] * MAXD + j] : 0.0f;
  }
  __syncthreads();

  float acc[TR];
  const float bj = b1[t * HDIM + j];
  #pragma unroll
  for (int r = 0; r < TR; ++r) acc[r] = bj;
  matvec_l<MAXD, 64>(W1 + (size_t)t * MAXD * HDIM, xl, acc, j);

  float m[TR], rs[TR];
  row_reduce(red, acc, m, rs, j);
  const float g1j = g1[t * HDIM + j], be1j = be1[t * HDIM + j];
  #pragma unroll
  for (int r = 0; r < TR; ++r)
    z[r * HDIM + j] = fmaxf((acc[r] - m[r]) * rs[r] * g1j + be1j, 0.0f);
  __syncthreads();

  const float b2j = b2[t * HDIM + j];
  #pragma unroll
  for (int r = 0; r < TR; ++r) acc[r] = b2j;
  matvec_l<HDIM, HDIM>(W2 + (size_t)t * HDIM * HDIM, z, acc, j);

  row_reduce(red, acc, m, rs, j);
  const float g2j = g2[t * HDIM + j], be2j = be2[t * HDIM + j];
  #pragma unroll
  for (int r = 0; r < TR; ++r)
    if (r < nr)
      hout[(size_t)rows[r] * HDIM + j] =
          fmaxf((acc[r] - m[r]) * rs[r] * g2j + be2j, 0.0f);
}

// ---------------- MFMA HGT hop ----------------

#define LDX 264  // padded LDS row stride (bf16 elems)

struct HopSmem {
  unsigned short xa[32 * LDX];
  unsigned short xi[32 * LDX];
  unsigned short msg[32 * LDX];
  float redS[32 * 4];
  float redQ[32 * 4];
  int rowsL[32];
};

__device__ __forceinline__ bf16x8 ldsA(const unsigned short* buf, int rf,
                                       int ks, int lane) {
  const int row = rf * 16 + (lane & 15);
  const int ko = ks * 32 + ((lane >> 4) << 3);
  return *(const bf16x8*)(buf + row * LDX + ko);
}

__device__ __forceinline__ bf16x8 gB(const unsigned short* __restrict__ W,
                                     int cf, int ks, int lane, int wid) {
  const int n = (wid << 6) + (cf << 4) + (lane & 15);
  const int ko = ks * 32 + ((lane >> 4) << 3);
  return *(const bf16x8*)(W + n * 256 + ko);
}

#define MFMA(a, b, c) __builtin_amdgcn_mfma_f32_16x16x32_bf16(a, b, c, 0, 0, 0)

__device__ __forceinline__ void hop_dir(
    const unsigned short* __restrict__ bq, const unsigned short* __restrict__ bk,
    const unsigned short* __restrict__ bv, const unsigned short* __restrict__ bo,
    const float* __restrict__ gg, const float* __restrict__ bb,
    const unsigned short* xdst, const unsigned short* xsrc,
    const float* __restrict__ hdst_g, float* __restrict__ hout_g,
    HopSmem& sm, const int mg[8], int lane, int wid) {
  // ---- q = Xdst*Wq, k = Xsrc*Wk (wave owns head `wid` = cols 64w..64w+63)
  f32x4 q[2][4] = {}; f32x4 kk[2][4] = {};
  #pragma unroll 2
  for (int ks = 0; ks < 8; ++ks) {
    bf16x8 ad0 = ldsA(xdst, 0, ks, lane), ad1 = ldsA(xdst, 1, ks, lane);
    bf16x8 as0 = ldsA(xsrc, 0, ks, lane), as1 = ldsA(xsrc, 1, ks, lane);
    #pragma unroll
    for (int cf = 0; cf < 4; ++cf) {
      bf16x8 wq = gB(bq, cf, ks, lane, wid);
      bf16x8 wk = gB(bk, cf, ks, lane, wid);
      q[0][cf]  = MFMA(ad0, wq, q[0][cf]);
      q[1][cf]  = MFMA(ad1, wq, q[1][cf]);
      kk[0][cf] = MFMA(as0, wk, kk[0][cf]);
      kk[1][cf] = MFMA(as1, wk, kk[1][cf]);
    }
  }
  // ---- attn[row] = sigmoid((q.k)_head / 8): reduce over 16 lanes (64 cols)
  float at[2][4];
  #pragma unroll
  for (int rf = 0; rf < 2; ++rf)
    #pragma unroll
    for (int rr = 0; rr < 4; ++rr) {
      float p = q[rf][0][rr] * kk[rf][0][rr] + q[rf][1][rr] * kk[rf][1][rr]
              + q[rf][2][rr] * kk[rf][2][rr] + q[rf][3][rr] * kk[rf][3][rr];
      p += __shfl_xor(p, 1); p += __shfl_xor(p, 2);
      p += __shfl_xor(p, 4); p += __shfl_xor(p, 8);
      at[rf][rr] = 1.0f / (1.0f + __expf(-p * 0.125f));
    }
  // ---- v = Xsrc*Wv
  f32x4 vv[2][4] = {};
  #pragma unroll 2
  for (int ks = 0; ks < 8; ++ks) {
    bf16x8 as0 = ldsA(xsrc, 0, ks, lane), as1 = ldsA(xsrc, 1, ks, lane);
    #pragma unroll
    for (int cf = 0; cf < 4; ++cf) {
      bf16x8 wv = gB(bv, cf, ks, lane, wid);
      vv[0][cf] = MFMA(as0, wv, vv[0][cf]);
      vv[1][cf] = MFMA(as1, wv, vv[1][cf]);
    }
  }
  // ---- msg = attn (.) v  -> LDS (bf16), C/D layout: col=lane&15, row=grp*4+rr
  __syncthreads();  // previous msg readers done
  #pragma unroll
  for (int rf = 0; rf < 2; ++rf)
    #pragma unroll
    for (int cf = 0; cf < 4; ++cf) {
      const int col = (wid << 6) + (cf << 4) + (lane & 15);
      #pragma unroll
      for (int rr = 0; rr < 4; ++rr) {
        const int row = rf * 16 + ((lane >> 4) << 2) + rr;
        sm.msg[row * LDX + col] = f2bf(vv[rf][cf][rr] * at[rf][rr]);
      }
    }
  __syncthreads();
  // ---- o = msg*Wo
  f32x4 oo[2][4] = {};
  #pragma unroll 2
  for (int ks = 0; ks < 8; ++ks) {
    bf16x8 am0 = ldsA(sm.msg, 0, ks, lane), am1 = ldsA(sm.msg, 1, ks, lane);
    #pragma unroll
    for (int cf = 0; cf < 4; ++cf) {
      bf16x8 wo = gB(bo, cf, ks, lane, wid);
      oo[0][cf] = MFMA(am0, wo, oo[0][cf]);
      oo[1][cf] = MFMA(am1, wo, oo[1][cf]);
    }
  }
  // ---- residual (fp32 re-read) + LN over 256 cols + write out
  float sums[2][4] = {}, sumq[2][4] = {};
  #pragma unroll
  for (int rf = 0; rf < 2; ++rf)
    #pragma unroll
    for (int cf = 0; cf < 4; ++cf) {
      const int col = (wid << 6) + (cf << 4) + (lane & 15);
      #pragma unroll
      for (int rr = 0; rr < 4; ++rr) {
        float x = hdst_g[(size_t)mg[rf * 4 + rr] * HDIM + col] + oo[rf][cf][rr];
        oo[rf][cf][rr] = x;
        sums[rf][rr] += x;
        sumq[rf][rr] += x * x;
      }
    }
  #pragma unroll
  for (int rf = 0; rf < 2; ++rf)
    #pragma unroll
    for (int rr = 0; rr < 4; ++rr) {
      float s = sums[rf][rr], z = sumq[rf][rr];
      s += __shfl_xor(s, 1); z += __shfl_xor(z, 1);
      s += __shfl_xor(s, 2); z += __shfl_xor(z, 2);
      s += __shfl_xor(s, 4); z += __shfl_xor(z, 4);
      s += __shfl_xor(s, 8); z += __shfl_xor(z, 8);
      sums[rf][rr] = s; sumq[rf][rr] = z;
    }
  __syncthreads();  // protect red buffers
  if ((lane & 15) == 0) {
    #pragma unroll
    for (int rf = 0; rf < 2; ++rf)
      #pragma unroll
      for (int rr = 0; rr < 4; ++rr) {
        const int row = rf * 16 + ((lane >> 4) << 2) + rr;
        sm.redS[row * 4 + wid] = sums[rf][rr];
        sm.redQ[row * 4 + wid] = sumq[rf][rr];
      }
  }
  __syncthreads();
  float g4[4], b4[4];
  #pragma unroll
  for (int cf = 0; cf < 4; ++cf) {
    const int col = (wid << 6) + (cf << 4) + (lane & 15);
    g4[cf] = gg[col]; b4[cf] = bb[col];
  }
  #pragma unroll
  for (int rf = 0; rf < 2; ++rf)
    #pragma unroll
    for (int rr = 0; rr < 4; ++rr) {
      const int row = rf * 16 + ((lane >> 4) << 2) + rr;
      float s = sm.redS[row * 4] + sm.redS[row * 4 + 1] +
                sm.redS[row * 4 + 2] + sm.redS[row * 4 + 3];
      float z = sm.redQ[row * 4] + sm.redQ[row * 4 + 1] +
                sm.redQ[row * 4 + 2] + sm.redQ[row * 4 + 3];
      float m  = s * (1.0f / HDIM);
      float rs = rsqrtf(z * (1.0f / HDIM) - m * m + 1e-5f);
      #pragma unroll
      for (int cf = 0; cf < 4; ++cf) {
        const int col = (wid << 6) + (cf << 4) + (lane & 15);
        hout_g[(size_t)mg[rf * 4 + rr] * HDIM + col] =
            (oo[rf][cf][rr] - m) * rs * g4[cf] + b4[cf];
      }
    }
}

__global__ __launch_bounds__(256) void hop_mfma_kernel(
    const unsigned short* __restrict__ bWk, const unsigned short* __restrict__ bWq,
    const unsigned short* __restrict__ bWv, const unsigned short* __restrict__ bWo,
    const float* __restrict__ g, const float* __restrict__ b,
    const int* __restrict__ idxC, const int* __restrict__ cnts,
    float* __restrict__ ha, float* __restrict__ hi) {
  const int c = blockIdx.y, a = c / 3, i = c % 3;
  const int cnt = cnts[6 + c];
  const int base = blockIdx.x * 32;
  if (base >= cnt) return;
  __shared__ HopSmem sm;
  const int tid = threadIdx.x;
  const int lane = tid & 63, wid = tid >> 6;

  if (tid < 32) {
    int rr = base + tid; if (rr > cnt - 1) rr = cnt - 1;
    sm.rowsL[tid] = idxC[c * BN + rr];
  }
  __syncthreads();
  // stage 32 rows of ha/hi as bf16 (2 cols/thread, 2 rows/iter)
  const int cp = (tid & 127) * 2, rh = tid >> 7;
  #pragma unroll 4
  for (int r0 = 0; r0 < 32; r0 += 2) {
    const int r = r0 + rh;
    const size_t gb = (size_t)sm.rowsL[r] * HDIM + cp;
    float2 va = *(const float2*)(ha + gb);
    float2 vi = *(const float2*)(hi + gb);
    *(unsigned*)(sm.xa + r * LDX + cp) =
        (unsigned)f2bf(va.x) | ((unsigned)f2bf(va.y) << 16);
    *(unsigned*)(sm.xi + r * LDX + cp) =
        (unsigned)f2bf(vi.x) | ((unsigned)f2bf(vi.y) << 16);
  }
  int mg[8];
  #pragma unroll
  for (int rf = 0; rf < 2; ++rf)
    #pragma unroll
    for (int rr = 0; rr < 4; ++rr)
      mg[rf * 4 + rr] = sm.rowsL[rf * 16 + ((lane >> 4) << 2) + rr];
  __syncthreads();

  const size_t MS = (size_t)HDIM * HDIM;
  const int e1 = i * 3 + a;  // item -> anchor, dst type a
  const int e2 = a * 3 + i;  // anchor -> item, dst type i
  hop_dir(bWq + e1 * MS, bWk + e1 * MS, bWv + e1 * MS, bWo + a * MS,
          g + a * HDIM, b + a * HDIM, sm.xa, sm.xi, ha, ha, sm, mg, lane, wid);
  hop_dir(bWq + e2 * MS, bWk + e2 * MS, bWv + e2 * MS, bWo + i * MS,
          g + i * HDIM, b + i * HDIM, sm.xi, sm.xa, hi, hi, sm, mg, lane, wid);
}

// ---------------- fp32 hop (fallback if ws too small) ----------------

__device__ __forceinline__ void hgt_dir_f32(
    const float* __restrict__ Wq, const float* __restrict__ Wk,
    const float* __restrict__ Wv, const float* __restrict__ Wo,
    const float* __restrict__ gg, const float* __restrict__ bb,
    const float* dstl, const float* srcl, float* msg, float* red, int j,
    float res[TR]) {
  float q[TR], kk[TR];
  #pragma unroll
  for (int r = 0; r < TR; ++r) { q[r] = 0.0f; kk[r] = 0.0f; }
  matvec_l<HDIM, HDIM>(Wq, dstl, q, j);
  matvec_l<HDIM, HDIM>(Wk, srcl, kk, j);
  float attn[TR];
  #pragma unroll
  for (int r = 0; r < TR; ++r) {
    float p = q[r] * kk[r];
    #pragma unroll
    for (int o = 32; o; o >>= 1) p += __shfl_xor(p, o);
    attn[r] = 1.0f / (1.0f + expf(-p * 0.125f));
  }
  #pragma unroll
  for (int r = 0; r < TR; ++r) q[r] = 0.0f;
  matvec_l<HDIM, HDIM>(Wv, srcl, q, j);
  __syncthreads();
  #pragma unroll
  for (int r = 0; r < TR; ++r) msg[r * HDIM + j] = attn[r] * q[r];
  __syncthreads();
  float o[TR];
  #pragma unroll
  for (int r = 0; r < TR; ++r) o[r] = 0.0f;
  matvec_l<HDIM, HDIM>(Wo, msg, o, j);
  float u[TR], m[TR], rs[TR];
  #pragma unroll
  for (int r = 0; r < TR; ++r) u[r] = dstl[r * HDIM + j] + o[r];
  row_reduce(red, u, m, rs, j);
  const float gj = gg[j], bj = bb[j];
  #pragma unroll
  for (int r = 0; r < TR; ++r) res[r] = (u[r] - m[r]) * rs[r] * gj + bj;
}

__global__ __launch_bounds__(256) void hop_kernel(
    const float* __restrict__ Wk, const float* __restrict__ Wq,
    const float* __restrict__ Wv, const float* __restrict__ Wout,
    const float* __restrict__ g, const float* __restrict__ b,
    const int* __restrict__ idxC, const int* __restrict__ cnts,
    float* __restrict__ ha, float* __restrict__ hi) {
  const int c = blockIdx.y, a = c / 3, i = c % 3;
  const int cnt = cnts[6 + c];
  const int base = blockIdx.x * TR;
  if (base >= cnt) return;
  const int nr = (cnt - base < TR) ? (cnt - base) : TR;
  const int j = threadIdx.x;
  __shared__ __align__(16) float xa[TR * HDIM];
  __shared__ __align__(16) float xi[TR * HDIM];
  __shared__ __align__(16) float msg[TR * HDIM];
  __shared__ float red[TR * 8];
  int rows[TR];
  #pragma unroll
  for (int r = 0; r < TR; ++r) {
    int rr = base + r; if (rr > cnt - 1) rr = cnt - 1;
    rows[r] = idxC[c * BN + rr];
  }
  #pragma unroll
  for (int r = 0; r < TR; ++r) {
    xa[r * HDIM + j] = ha[(size_t)rows[r] * HDIM + j];
    xi[r * HDIM + j] = hi[(size_t)rows[r] * HDIM + j];
  }
  __syncthreads();
  const int e1 = i * 3 + a, e2 = a * 3 + i;
  float res1[TR], res2[TR];
  hgt_dir_f32(Wq + (size_t)e1 * HDIM * HDIM, Wk + (size_t)e1 * HDIM * HDIM,
              Wv + (size_t)e1 * HDIM * HDIM, Wout + (size_t)a * HDIM * HDIM,
              g + a * HDIM, b + a * HDIM, xa, xi, msg, red, j, res1);
  hgt_dir_f32(Wq + (size_t)e2 * HDIM * HDIM, Wk + (size_t)e2 * HDIM * HDIM,
              Wv + (size_t)e2 * HDIM * HDIM, Wout + (size_t)i * HDIM * HDIM,
              g + i * HDIM, b + i * HDIM, xi, xa, msg, red, j, res2);
  #pragma unroll
  for (int r = 0; r < TR; ++r)
    if (r < nr) {
      ha[(size_t)rows[r] * HDIM + j] = res1[r];
      hi[(size_t)rows[r] * HDIM + j] = res2[r];
    }
}

// ---------------- output projection + LN + l2norm ----------------

__global__ __launch_bounds__(256) void out_kernel(
    const float* __restrict__ W, const float* __restrict__ bb,
    const float* __restrict__ g, const float* __restrict__ be,
    float* __restrict__ out) {
  const int ent = blockIdx.y;
  const int base = blockIdx.x * TR;
  const int j = threadIdx.x;
  float* hsrc = out + (size_t)ent * BN * HDIM;
  __shared__ __align__(16) float xl[TR * HDIM];
  __shared__ float red[TR * 8];
  #pragma unroll
  for (int r = 0; r < TR; ++r)
    xl[r * HDIM + j] = hsrc[(size_t)(base + r) * HDIM + j];
  __syncthreads();
  float acc[TR];
  const float bj = bb[j];
  #pragma unroll
  for (int r = 0; r < TR; ++r) acc[r] = bj;
  matvec_l<HDIM, HDIM>(W, xl, acc, j);
  float m[TR], rs[TR];
  row_reduce(red, acc, m, rs, j);
  const float gj = g[j], bej = be[j];
  float y[TR];
  #pragma unroll
  for (int r = 0; r < TR; ++r) y[r] = (acc[r] - m[r]) * rs[r] * gj + bej;
  const int lane = j & 63, wv = j >> 6;
  __syncthreads();
  #pragma unroll
  for (int r = 0; r < TR; ++r) {
    float p = y[r] * y[r];
    #pragma unroll
    for (int o = 32; o; o >>= 1) p += __shfl_xor(p, o);
    if (lane == 0) red[r * 4 + wv] = p;
  }
  __syncthreads();
  #pragma unroll
  for (int r = 0; r < TR; ++r) {
    float ss = red[r * 4] + red[r * 4 + 1] + red[r * 4 + 2] + red[r * 4 + 3];
    float inv = 1.0f / fmaxf(sqrtf(ss), 1e-12f);
    hsrc[(size_t)(base + r) * HDIM + j] = y[r] * inv;
  }
}

// ---------------- launch ----------------

extern "C" void kernel_launch(void* const* d_in, const int* in_sizes, int n_in,
                              void* d_out, int out_size, void* d_ws,
                              size_t ws_size, hipStream_t stream) {
  const float* af   = (const float*)d_in[0];
  const float* itf  = (const float*)d_in[1];
  const int*   atid = (const int*)d_in[2];
  const int*   itid = (const int*)d_in[3];
  const float* eW1  = (const float*)d_in[4];
  const float* eb1  = (const float*)d_in[5];
  const float* eg1  = (const float*)d_in[6];
  const float* ebe1 = (const float*)d_in[7];
  const float* eW2  = (const float*)d_in[8];
  const float* eb2  = (const float*)d_in[9];
  const float* eg2  = (const float*)d_in[10];
  const float* ebe2 = (const float*)d_in[11];
  const float* hWk  = (const float*)d_in[12];
  const float* hWq  = (const float*)d_in[13];
  const float* hWv  = (const float*)d_in[14];
  const float* hWo  = (const float*)d_in[15];
  const float* hg   = (const float*)d_in[16];
  const float* hb   = (const float*)d_in[17];
  const float* oW   = (const float*)d_in[18];
  const float* ob   = (const float*)d_in[19];
  const float* og   = (const float*)d_in[20];
  const float* obe  = (const float*)d_in[21];

  float* out = (float*)d_out;
  float* ha = out;
  float* hi = out + (size_t)BN * HDIM;

  int* cnts = (int*)d_ws;
  int* idxA = cnts + 16;
  int* idxI = idxA + 3 * BN;
  int* idxC = idxI + 3 * BN;
  unsigned short* bWk = (unsigned short*)(idxC + 9 * BN);  // 18*65536
  unsigned short* bWq = bWk + 18 * 65536;
  unsigned short* bWv = bWq + 18 * 65536;
  unsigned short* bWo = bWv + 18 * 65536;                  // 6*65536
  const size_t ws_need = (size_t)(16 + 15 * BN) * 4 + (size_t)60 * 65536 * 2;
  const bool use_mfma = ws_size >= ws_need;

  hipMemsetAsync(cnts, 0, 16 * sizeof(int), stream);
  bucket_kernel<<<BN / 256, 256, 0, stream>>>(atid, itid, cnts, idxA, idxI, idxC);
  if (use_mfma)
    wconv_kernel<<<60 * 256, 256, 0, stream>>>(hWk, hWq, hWv, hWo,
                                               bWk, bWq, bWv, bWo);

  dim3 genc((BN + TR - 1) / TR, 3, 2);
  enc_kernel<<<genc, 256, 0, stream>>>(af, itf, idxA, idxI, cnts,
                                       eW1, eb1, eg1, ebe1, eW2, eb2, eg2, ebe2,
                                       ha, hi);

  for (int L = 0; L < 2; ++L) {
    if (use_mfma) {
      hop_mfma_kernel<<<dim3(BN / 32, 9), 256, 0, stream>>>(
          bWk + (size_t)L * 9 * 65536, bWq + (size_t)L * 9 * 65536,
          bWv + (size_t)L * 9 * 65536, bWo + (size_t)L * 3 * 65536,
          hg + L * 3 * HDIM, hb + L * 3 * HDIM, idxC, cnts, ha, hi);
    } else {
      hop_kernel<<<dim3((BN + TR - 1) / TR, 9), 256, 0, stream>>>(
          hWk + (size_t)L * 9 * HDIM * HDIM, hWq + (size_t)L * 9 * HDIM * HDIM,
          hWv + (size_t)L * 9 * HDIM * HDIM, hWo + (size_t)L * 3 * HDIM * HDIM,
          hg + L * 3 * HDIM, hb + L * 3 * HDIM, idxC, cnts, ha, hi);
    }
  }

  out_kernel<<<dim3(BN / TR, 2), 256, 0, stream>>>(oW, ob, og, obe, out);
}

// Round 3
// 324.209 us; speedup vs baseline: 17.6154x; 2.9435x over previous
//
#include <hip/hip_runtime.h>
#include <math.h>

#define BN   32768
#define MAXD 60
#define HDIM 256
#define TR   16
#define LDX  264  // padded LDS row stride (bf16 elems) for K=256 tiles

typedef __attribute__((ext_vector_type(4))) float f32x4;
typedef __attribute__((ext_vector_type(8))) short bf16x8;

#define MFMA(a, b, c) __builtin_amdgcn_mfma_f32_16x16x32_bf16(a, b, c, 0, 0, 0)

__device__ __forceinline__ unsigned short f2bf(float f) {
  union { float f; unsigned u; } v; v.f = f;
  unsigned r = v.u + 0x7FFF + ((v.u >> 16) & 1);
  return (unsigned short)(r >> 16);
}

// A-fragment read from LDS tile with row stride LDXE (bf16 elems).
template <int LDXE>
__device__ __forceinline__ bf16x8 ldsAx(const unsigned short* buf, int rf,
                                        int ks, int lane) {
  const int row = rf * 16 + (lane & 15);
  const int ko = ks * 32 + ((lane >> 4) << 3);
  return *(const bf16x8*)(buf + row * LDXE + ko);
}

// B-fragment from frag-linear packed weights: contiguous 1KB per wave read.
template <int KS>
__device__ __forceinline__ bf16x8 fragB(const unsigned short* __restrict__ W,
                                        int cfw, int ks, int lane) {
  return *(const bf16x8*)(W + ((size_t)(cfw * KS + ks) << 9) + (lane << 3));
}

__device__ __forceinline__ float red16(float p) {
  p += __shfl_xor(p, 1); p += __shfl_xor(p, 2);
  p += __shfl_xor(p, 4); p += __shfl_xor(p, 8);
  return p;
}

// Cross-wave LN stats: sums/sumq already reduced over 16 lanes.
__device__ __forceinline__ void cross_ln(float* redS, float* redQ,
                                         const float sums[2][4],
                                         const float sumq[2][4], int lane,
                                         int wid, float mo[2][4],
                                         float ro[2][4]) {
  __syncthreads();
  if ((lane & 15) == 0) {
    #pragma unroll
    for (int rf = 0; rf < 2; ++rf)
      #pragma unroll
      for (int rr = 0; rr < 4; ++rr) {
        const int row = rf * 16 + ((lane >> 4) << 2) + rr;
        redS[row * 4 + wid] = sums[rf][rr];
        redQ[row * 4 + wid] = sumq[rf][rr];
      }
  }
  __syncthreads();
  #pragma unroll
  for (int rf = 0; rf < 2; ++rf)
    #pragma unroll
    for (int rr = 0; rr < 4; ++rr) {
      const int row = rf * 16 + ((lane >> 4) << 2) + rr;
      float s = redS[row * 4] + redS[row * 4 + 1] + redS[row * 4 + 2] + redS[row * 4 + 3];
      float z = redQ[row * 4] + redQ[row * 4 + 1] + redQ[row * 4 + 2] + redQ[row * 4 + 3];
      float m = s * (1.0f / HDIM);
      mo[rf][rr] = m;
      ro[rf][rr] = rsqrtf(z * (1.0f / HDIM) - m * m + 1e-5f);
    }
}

// ---------------- fp32 helpers (fallback path) ----------------

__device__ __forceinline__ void row_reduce(float* red, const float acc[TR],
                                           float m[TR], float rs[TR], int j) {
  const int lane = j & 63, wv = j >> 6;
  __syncthreads();
  #pragma unroll
  for (int r = 0; r < TR; ++r) {
    float s = acc[r], q = acc[r] * acc[r];
    #pragma unroll
    for (int o = 32; o; o >>= 1) { s += __shfl_xor(s, o); q += __shfl_xor(q, o); }
    if (lane == 0) { red[r * 8 + wv * 2] = s; red[r * 8 + wv * 2 + 1] = q; }
  }
  __syncthreads();
  #pragma unroll
  for (int r = 0; r < TR; ++r) {
    float s = red[r * 8 + 0] + red[r * 8 + 2] + red[r * 8 + 4] + red[r * 8 + 6];
    float q = red[r * 8 + 1] + red[r * 8 + 3] + red[r * 8 + 5] + red[r * 8 + 7];
    float mean = s * (1.0f / HDIM);
    float var  = q * (1.0f / HDIM) - mean * mean;
    m[r]  = mean;
    rs[r] = rsqrtf(var + 1e-5f);
  }
}

template <int KD, int ST>
__device__ __forceinline__ void matvec_l(const float* __restrict__ W,
                                         const float* zz, float acc[TR], int j) {
  #pragma unroll 2
  for (int k = 0; k < KD; k += 4) {
    const float w0 = W[(k + 0) * HDIM + j];
    const float w1 = W[(k + 1) * HDIM + j];
    const float w2 = W[(k + 2) * HDIM + j];
    const float w3 = W[(k + 3) * HDIM + j];
    #pragma unroll
    for (int r = 0; r < TR; ++r) {
      const float4 x = *(const float4*)(zz + r * ST + k);
      acc[r] = fmaf(x.w, w3, fmaf(x.z, w2, fmaf(x.y, w1, fmaf(x.x, w0, acc[r]))));
    }
  }
}

// ---------------- bucketing ----------------

__global__ __launch_bounds__(256) void bucket_kernel(
    const int* __restrict__ atid, const int* __restrict__ itid,
    int* cnts, int* idxA, int* idxI, int* idxC) {
  __shared__ int lcnt[15], lbase[15];
  const int tid = threadIdx.x;
  const int r = blockIdx.x * 256 + tid;
  if (tid < 15) lcnt[tid] = 0;
  __syncthreads();
  const int a = atid[r], i = itid[r];
  const int c = a * 3 + i;
  const int la = atomicAdd(&lcnt[a], 1);
  const int li = atomicAdd(&lcnt[3 + i], 1);
  const int lc = atomicAdd(&lcnt[6 + c], 1);
  __syncthreads();
  if (tid < 15) lbase[tid] = atomicAdd(&cnts[tid], lcnt[tid]);
  __syncthreads();
  idxA[a * BN + lbase[a] + la] = r;
  idxI[i * BN + lbase[3 + i] + li] = r;
  idxC[c * BN + lbase[6 + c] + lc] = r;
}

// ---------------- weight pack: fp32 [k][n] -> bf16 frag-linear ----------------
// dst layout per matrix: idx = ((wid*4+cf)*KS + ks)*512 + lane*8 + e
// maps to (n = wid*64+cf*16+(lane&15), k = ks*32+(lane>>4)*8+e); zero if k>=srcK.

__global__ __launch_bounds__(256) void wpack_kernel(
    const float* __restrict__ src, unsigned short* __restrict__ dst,
    int nmat, int KS, int srcK) {
  const int per = KS * 8192;
  const int idx = blockIdx.x * 256 + threadIdx.x;
  const int m = idx / per;
  if (m >= nmat) return;
  const int r = idx % per;
  const int e = r & 7;
  const int lane = (r >> 3) & 63;
  const int t = r >> 9;
  const int ks = t % KS;
  const int cfw = t / KS;
  const int n = ((cfw >> 2) << 6) + ((cfw & 3) << 4) + (lane & 15);
  const int k = (ks << 5) + ((lane >> 4) << 3) + e;
  const float v = (k < srcK) ? src[(size_t)m * srcK * 256 + (size_t)k * 256 + n] : 0.0f;
  dst[idx] = f2bf(v);
}

// ---------------- MFMA encoder ----------------

struct EncSmem {
  unsigned short x1[32 * 72];   // layer1 input, K=64 (zero-padded), stride 72
  unsigned short z[32 * LDX];   // layer2 input
  float redS[32 * 4];
  float redQ[32 * 4];
  int rowsL[32];
};

__global__ __launch_bounds__(256) void enc_mfma_kernel(
    const float* __restrict__ af, const float* __restrict__ itf,
    const int* __restrict__ idxA, const int* __restrict__ idxI,
    const int* __restrict__ cnts,
    const unsigned short* __restrict__ pW1, const unsigned short* __restrict__ pW2,
    const float* __restrict__ b1, const float* __restrict__ g1,
    const float* __restrict__ be1, const float* __restrict__ b2,
    const float* __restrict__ g2, const float* __restrict__ be2,
    float* __restrict__ ha, float* __restrict__ hi) {
  const int t = blockIdx.y, ent = blockIdx.z;
  const int cnt = cnts[ent * 3 + t];
  const int base = blockIdx.x * 32;
  if (base >= cnt) return;
  const float* feats = ent ? itf : af;
  const int* idx = (ent ? idxI : idxA) + t * BN;
  float* hout = ent ? hi : ha;
  __shared__ EncSmem sm;
  const int tid = threadIdx.x, lane = tid & 63, wid = tid >> 6;

  if (tid < 32) {
    int rr = base + tid; if (rr > cnt - 1) rr = cnt - 1;
    sm.rowsL[tid] = idx[rr];
  }
  __syncthreads();
  {  // stage 32 rows x 64 cols bf16 (zero pad cols >= 60)
    const int c2 = (tid & 31) * 2, rh = tid >> 5;
    #pragma unroll
    for (int p = 0; p < 4; ++p) {
      const int r = p * 8 + rh;
      unsigned val = 0;
      if (c2 < MAXD) {
        const float2 v = *(const float2*)(feats + (size_t)sm.rowsL[r] * MAXD + c2);
        val = (unsigned)f2bf(v.x) | ((unsigned)f2bf(v.y) << 16);
      }
      *(unsigned*)(sm.x1 + r * 72 + c2) = val;
    }
  }
  int mg[8];
  #pragma unroll
  for (int rf = 0; rf < 2; ++rf)
    #pragma unroll
    for (int rr = 0; rr < 4; ++rr)
      mg[rf * 4 + rr] = sm.rowsL[rf * 16 + ((lane >> 4) << 2) + rr];
  __syncthreads();

  // ---- layer 1: K=64
  f32x4 acc[2][4] = {};
  #pragma unroll
  for (int ks = 0; ks < 2; ++ks) {
    bf16x8 a0 = ldsAx<72>(sm.x1, 0, ks, lane);
    bf16x8 a1 = ldsAx<72>(sm.x1, 1, ks, lane);
    #pragma unroll
    for (int cf = 0; cf < 4; ++cf) {
      bf16x8 w = fragB<2>(pW1 + (size_t)t * 16384, (wid << 2) + cf, ks, lane);
      acc[0][cf] = MFMA(a0, w, acc[0][cf]);
      acc[1][cf] = MFMA(a1, w, acc[1][cf]);
    }
  }
  float cb[4], cg[4], cbe[4];
  #pragma unroll
  for (int cf = 0; cf < 4; ++cf) {
    const int col = (wid << 6) + (cf << 4) + (lane & 15);
    cb[cf] = b1[t * HDIM + col]; cg[cf] = g1[t * HDIM + col]; cbe[cf] = be1[t * HDIM + col];
  }
  float sums[2][4] = {}, sumq[2][4] = {};
  #pragma unroll
  for (int rf = 0; rf < 2; ++rf)
    #pragma unroll
    for (int cf = 0; cf < 4; ++cf)
      #pragma unroll
      for (int rr = 0; rr < 4; ++rr) {
        float x = acc[rf][cf][rr] + cb[cf];
        acc[rf][cf][rr] = x;
        sums[rf][rr] += x; sumq[rf][rr] += x * x;
      }
  #pragma unroll
  for (int rf = 0; rf < 2; ++rf)
    #pragma unroll
    for (int rr = 0; rr < 4; ++rr) { sums[rf][rr] = red16(sums[rf][rr]); sumq[rf][rr] = red16(sumq[rf][rr]); }
  float m[2][4], rs[2][4];
  cross_ln(sm.redS, sm.redQ, sums, sumq, lane, wid, m, rs);
  #pragma unroll
  for (int rf = 0; rf < 2; ++rf)
    #pragma unroll
    for (int cf = 0; cf < 4; ++cf) {
      const int col = (wid << 6) + (cf << 4) + (lane & 15);
      #pragma unroll
      for (int rr = 0; rr < 4; ++rr) {
        const int row = rf * 16 + ((lane >> 4) << 2) + rr;
        float zz = fmaxf((acc[rf][cf][rr] - m[rf][rr]) * rs[rf][rr] * cg[cf] + cbe[cf], 0.0f);
        sm.z[row * LDX + col] = f2bf(zz);
      }
    }
  __syncthreads();

  // ---- layer 2: K=256
  #pragma unroll
  for (int rf = 0; rf < 2; ++rf)
    #pragma unroll
    for (int cf = 0; cf < 4; ++cf) acc[rf][cf] = (f32x4){0.f, 0.f, 0.f, 0.f};
  #pragma unroll 2
  for (int ks = 0; ks < 8; ++ks) {
    bf16x8 a0 = ldsAx<LDX>(sm.z, 0, ks, lane);
    bf16x8 a1 = ldsAx<LDX>(sm.z, 1, ks, lane);
    #pragma unroll
    for (int cf = 0; cf < 4; ++cf) {
      bf16x8 w = fragB<8>(pW2 + (size_t)t * 65536, (wid << 2) + cf, ks, lane);
      acc[0][cf] = MFMA(a0, w, acc[0][cf]);
      acc[1][cf] = MFMA(a1, w, acc[1][cf]);
    }
  }
  #pragma unroll
  for (int cf = 0; cf < 4; ++cf) {
    const int col = (wid << 6) + (cf << 4) + (lane & 15);
    cb[cf] = b2[t * HDIM + col]; cg[cf] = g2[t * HDIM + col]; cbe[cf] = be2[t * HDIM + col];
  }
  float sums2[2][4] = {}, sumq2[2][4] = {};
  #pragma unroll
  for (int rf = 0; rf < 2; ++rf)
    #pragma unroll
    for (int cf = 0; cf < 4; ++cf)
      #pragma unroll
      for (int rr = 0; rr < 4; ++rr) {
        float x = acc[rf][cf][rr] + cb[cf];
        acc[rf][cf][rr] = x;
        sums2[rf][rr] += x; sumq2[rf][rr] += x * x;
      }
  #pragma unroll
  for (int rf = 0; rf < 2; ++rf)
    #pragma unroll
    for (int rr = 0; rr < 4; ++rr) { sums2[rf][rr] = red16(sums2[rf][rr]); sumq2[rf][rr] = red16(sumq2[rf][rr]); }
  cross_ln(sm.redS, sm.redQ, sums2, sumq2, lane, wid, m, rs);
  #pragma unroll
  for (int rf = 0; rf < 2; ++rf)
    #pragma unroll
    for (int cf = 0; cf < 4; ++cf) {
      const int col = (wid << 6) + (cf << 4) + (lane & 15);
      #pragma unroll
      for (int rr = 0; rr < 4; ++rr)
        hout[(size_t)mg[rf * 4 + rr] * HDIM + col] =
            fmaxf((acc[rf][cf][rr] - m[rf][rr]) * rs[rf][rr] * cg[cf] + cbe[cf], 0.0f);
    }
}

// ---------------- MFMA HGT hop ----------------

struct HopSmem {
  unsigned short xa[32 * LDX];
  unsigned short xi[32 * LDX];
  unsigned short msg[32 * LDX];
  float redS[32 * 4];
  float redQ[32 * 4];
  int rowsL[32];
};

__device__ __forceinline__ void hop_dir(
    const unsigned short* __restrict__ bq, const unsigned short* __restrict__ bk,
    const unsigned short* __restrict__ bv, const unsigned short* __restrict__ bo,
    const float* __restrict__ gg, const float* __restrict__ bb,
    const unsigned short* xdst, const unsigned short* xsrc,
    const float* __restrict__ hdst_g, float* __restrict__ hout_g,
    HopSmem& sm, const int mg[8], int lane, int wid) {
  // q = Xdst*Wq, k = Xsrc*Wk (wave owns head wid = cols 64w..64w+63)
  f32x4 q[2][4] = {}; f32x4 kk[2][4] = {};
  #pragma unroll 2
  for (int ks = 0; ks < 8; ++ks) {
    bf16x8 ad0 = ldsAx<LDX>(xdst, 0, ks, lane), ad1 = ldsAx<LDX>(xdst, 1, ks, lane);
    bf16x8 as0 = ldsAx<LDX>(xsrc, 0, ks, lane), as1 = ldsAx<LDX>(xsrc, 1, ks, lane);
    #pragma unroll
    for (int cf = 0; cf < 4; ++cf) {
      bf16x8 wq = fragB<8>(bq, (wid << 2) + cf, ks, lane);
      bf16x8 wk = fragB<8>(bk, (wid << 2) + cf, ks, lane);
      q[0][cf]  = MFMA(ad0, wq, q[0][cf]);
      q[1][cf]  = MFMA(ad1, wq, q[1][cf]);
      kk[0][cf] = MFMA(as0, wk, kk[0][cf]);
      kk[1][cf] = MFMA(as1, wk, kk[1][cf]);
    }
  }
  float at[2][4];
  #pragma unroll
  for (int rf = 0; rf < 2; ++rf)
    #pragma unroll
    for (int rr = 0; rr < 4; ++rr) {
      float p = q[rf][0][rr] * kk[rf][0][rr] + q[rf][1][rr] * kk[rf][1][rr]
              + q[rf][2][rr] * kk[rf][2][rr] + q[rf][3][rr] * kk[rf][3][rr];
      p = red16(p);
      at[rf][rr] = 1.0f / (1.0f + __expf(-p * 0.125f));
    }
  // v = Xsrc*Wv
  f32x4 vv[2][4] = {};
  #pragma unroll 2
  for (int ks = 0; ks < 8; ++ks) {
    bf16x8 as0 = ldsAx<LDX>(xsrc, 0, ks, lane), as1 = ldsAx<LDX>(xsrc, 1, ks, lane);
    #pragma unroll
    for (int cf = 0; cf < 4; ++cf) {
      bf16x8 wv = fragB<8>(bv, (wid << 2) + cf, ks, lane);
      vv[0][cf] = MFMA(as0, wv, vv[0][cf]);
      vv[1][cf] = MFMA(as1, wv, vv[1][cf]);
    }
  }
  // msg = attn (.) v -> LDS bf16
  __syncthreads();
  #pragma unroll
  for (int rf = 0; rf < 2; ++rf)
    #pragma unroll
    for (int cf = 0; cf < 4; ++cf) {
      const int col = (wid << 6) + (cf << 4) + (lane & 15);
      #pragma unroll
      for (int rr = 0; rr < 4; ++rr) {
        const int row = rf * 16 + ((lane >> 4) << 2) + rr;
        sm.msg[row * LDX + col] = f2bf(vv[rf][cf][rr] * at[rf][rr]);
      }
    }
  __syncthreads();
  // o = msg*Wo
  f32x4 oo[2][4] = {};
  #pragma unroll 2
  for (int ks = 0; ks < 8; ++ks) {
    bf16x8 am0 = ldsAx<LDX>(sm.msg, 0, ks, lane), am1 = ldsAx<LDX>(sm.msg, 1, ks, lane);
    #pragma unroll
    for (int cf = 0; cf < 4; ++cf) {
      bf16x8 wo = fragB<8>(bo, (wid << 2) + cf, ks, lane);
      oo[0][cf] = MFMA(am0, wo, oo[0][cf]);
      oo[1][cf] = MFMA(am1, wo, oo[1][cf]);
    }
  }
  // residual (fp32 re-read) + LN + write
  float sums[2][4] = {}, sumq[2][4] = {};
  #pragma unroll
  for (int rf = 0; rf < 2; ++rf)
    #pragma unroll
    for (int cf = 0; cf < 4; ++cf) {
      const int col = (wid << 6) + (cf << 4) + (lane & 15);
      #pragma unroll
      for (int rr = 0; rr < 4; ++rr) {
        float x = hdst_g[(size_t)mg[rf * 4 + rr] * HDIM + col] + oo[rf][cf][rr];
        oo[rf][cf][rr] = x;
        sums[rf][rr] += x;
        sumq[rf][rr] += x * x;
      }
    }
  #pragma unroll
  for (int rf = 0; rf < 2; ++rf)
    #pragma unroll
    for (int rr = 0; rr < 4; ++rr) { sums[rf][rr] = red16(sums[rf][rr]); sumq[rf][rr] = red16(sumq[rf][rr]); }
  float m[2][4], rs[2][4];
  cross_ln(sm.redS, sm.redQ, sums, sumq, lane, wid, m, rs);
  float g4[4], b4[4];
  #pragma unroll
  for (int cf = 0; cf < 4; ++cf) {
    const int col = (wid << 6) + (cf << 4) + (lane & 15);
    g4[cf] = gg[col]; b4[cf] = bb[col];
  }
  #pragma unroll
  for (int rf = 0; rf < 2; ++rf)
    #pragma unroll
    for (int rr = 0; rr < 4; ++rr) {
      #pragma unroll
      for (int cf = 0; cf < 4; ++cf) {
        const int col = (wid << 6) + (cf << 4) + (lane & 15);
        hout_g[(size_t)mg[rf * 4 + rr] * HDIM + col] =
            (oo[rf][cf][rr] - m[rf][rr]) * rs[rf][rr] * g4[cf] + b4[cf];
      }
    }
}

__global__ __launch_bounds__(256) void hop_mfma_kernel(
    const unsigned short* __restrict__ bWk, const unsigned short* __restrict__ bWq,
    const unsigned short* __restrict__ bWv, const unsigned short* __restrict__ bWo,
    const float* __restrict__ g, const float* __restrict__ b,
    const int* __restrict__ idxC, const int* __restrict__ cnts,
    float* __restrict__ ha, float* __restrict__ hi) {
  const int c = blockIdx.y, a = c / 3, i = c % 3;
  const int cnt = cnts[6 + c];
  const int base = blockIdx.x * 32;
  if (base >= cnt) return;
  __shared__ HopSmem sm;
  const int tid = threadIdx.x;
  const int lane = tid & 63, wid = tid >> 6;

  if (tid < 32) {
    int rr = base + tid; if (rr > cnt - 1) rr = cnt - 1;
    sm.rowsL[tid] = idxC[c * BN + rr];
  }
  __syncthreads();
  const int cp = (tid & 127) * 2, rh = tid >> 7;
  #pragma unroll 4
  for (int r0 = 0; r0 < 32; r0 += 2) {
    const int r = r0 + rh;
    const size_t gb = (size_t)sm.rowsL[r] * HDIM + cp;
    float2 va = *(const float2*)(ha + gb);
    float2 vi = *(const float2*)(hi + gb);
    *(unsigned*)(sm.xa + r * LDX + cp) =
        (unsigned)f2bf(va.x) | ((unsigned)f2bf(va.y) << 16);
    *(unsigned*)(sm.xi + r * LDX + cp) =
        (unsigned)f2bf(vi.x) | ((unsigned)f2bf(vi.y) << 16);
  }
  int mg[8];
  #pragma unroll
  for (int rf = 0; rf < 2; ++rf)
    #pragma unroll
    for (int rr = 0; rr < 4; ++rr)
      mg[rf * 4 + rr] = sm.rowsL[rf * 16 + ((lane >> 4) << 2) + rr];
  __syncthreads();

  const size_t MS = (size_t)HDIM * HDIM;
  const int e1 = i * 3 + a;  // item -> anchor, dst type a
  const int e2 = a * 3 + i;  // anchor -> item, dst type i
  hop_dir(bWq + e1 * MS, bWk + e1 * MS, bWv + e1 * MS, bWo + a * MS,
          g + a * HDIM, b + a * HDIM, sm.xa, sm.xi, ha, ha, sm, mg, lane, wid);
  hop_dir(bWq + e2 * MS, bWk + e2 * MS, bWv + e2 * MS, bWo + i * MS,
          g + i * HDIM, b + i * HDIM, sm.xi, sm.xa, hi, hi, sm, mg, lane, wid);
}

// ---------------- MFMA output projection + LN + l2norm ----------------

struct OutSmem {
  unsigned short x[32 * LDX];
  float redS[32 * 4];
  float redQ[32 * 4];
};

__global__ __launch_bounds__(256) void out_mfma_kernel(
    const unsigned short* __restrict__ pW, const float* __restrict__ bb,
    const float* __restrict__ g, const float* __restrict__ be,
    float* __restrict__ out) {
  const int ent = blockIdx.y;
  const int base = blockIdx.x * 32;
  float* hsrc = out + (size_t)ent * BN * HDIM;
  __shared__ OutSmem sm;
  const int tid = threadIdx.x, lane = tid & 63, wid = tid >> 6;
  const int cp = (tid & 127) * 2, rh = tid >> 7;
  #pragma unroll 4
  for (int r0 = 0; r0 < 32; r0 += 2) {
    const int r = r0 + rh;
    const float2 v = *(const float2*)(hsrc + (size_t)(base + r) * HDIM + cp);
    *(unsigned*)(sm.x + r * LDX + cp) =
        (unsigned)f2bf(v.x) | ((unsigned)f2bf(v.y) << 16);
  }
  __syncthreads();
  f32x4 acc[2][4] = {};
  #pragma unroll 2
  for (int ks = 0; ks < 8; ++ks) {
    bf16x8 a0 = ldsAx<LDX>(sm.x, 0, ks, lane);
    bf16x8 a1 = ldsAx<LDX>(sm.x, 1, ks, lane);
    #pragma unroll
    for (int cf = 0; cf < 4; ++cf) {
      bf16x8 w = fragB<8>(pW, (wid << 2) + cf, ks, lane);
      acc[0][cf] = MFMA(a0, w, acc[0][cf]);
      acc[1][cf] = MFMA(a1, w, acc[1][cf]);
    }
  }
  float cb[4], cg[4], cbe[4];
  #pragma unroll
  for (int cf = 0; cf < 4; ++cf) {
    const int col = (wid << 6) + (cf << 4) + (lane & 15);
    cb[cf] = bb[col]; cg[cf] = g[col]; cbe[cf] = be[col];
  }
  float sums[2][4] = {}, sumq[2][4] = {};
  #pragma unroll
  for (int rf = 0; rf < 2; ++rf)
    #pragma unroll
    for (int cf = 0; cf < 4; ++cf)
      #pragma unroll
      for (int rr = 0; rr < 4; ++rr) {
        float x = acc[rf][cf][rr] + cb[cf];
        acc[rf][cf][rr] = x;
        sums[rf][rr] += x; sumq[rf][rr] += x * x;
      }
  #pragma unroll
  for (int rf = 0; rf < 2; ++rf)
    #pragma unroll
    for (int rr = 0; rr < 4; ++rr) { sums[rf][rr] = red16(sums[rf][rr]); sumq[rf][rr] = red16(sumq[rf][rr]); }
  float m[2][4], rs[2][4];
  cross_ln(sm.redS, sm.redQ, sums, sumq, lane, wid, m, rs);
  // LN then l2 norm
  float s2[2][4] = {};
  #pragma unroll
  for (int rf = 0; rf < 2; ++rf)
    #pragma unroll
    for (int cf = 0; cf < 4; ++cf)
      #pragma unroll
      for (int rr = 0; rr < 4; ++rr) {
        float y = (acc[rf][cf][rr] - m[rf][rr]) * rs[rf][rr] * cg[cf] + cbe[cf];
        acc[rf][cf][rr] = y;
        s2[rf][rr] += y * y;
      }
  #pragma unroll
  for (int rf = 0; rf < 2; ++rf)
    #pragma unroll
    for (int rr = 0; rr < 4; ++rr) s2[rf][rr] = red16(s2[rf][rr]);
  __syncthreads();
  if ((lane & 15) == 0) {
    #pragma unroll
    for (int rf = 0; rf < 2; ++rf)
      #pragma unroll
      for (int rr = 0; rr < 4; ++rr) {
        const int row = rf * 16 + ((lane >> 4) << 2) + rr;
        sm.redS[row * 4 + wid] = s2[rf][rr];
      }
  }
  __syncthreads();
  #pragma unroll
  for (int rf = 0; rf < 2; ++rf)
    #pragma unroll
    for (int rr = 0; rr < 4; ++rr) {
      const int row = rf * 16 + ((lane >> 4) << 2) + rr;
      float ss = sm.redS[row * 4] + sm.redS[row * 4 + 1] +
                 sm.redS[row * 4 + 2] + sm.redS[row * 4 + 3];
      float inv = 1.0f / fmaxf(sqrtf(ss), 1e-12f);
      #pragma unroll
      for (int cf = 0; cf < 4; ++cf) {
        const int col = (wid << 6) + (cf << 4) + (lane & 15);
        hsrc[(size_t)(base + row) * HDIM + col] = acc[rf][cf][rr] * inv;
      }
    }
}

// ---------------- fp32 fallback kernels ----------------

__global__ __launch_bounds__(256) void enc_kernel(
    const float* __restrict__ af, const float* __restrict__ itf,
    const int* __restrict__ idxA, const int* __restrict__ idxI,
    const int* __restrict__ cnts,
    const float* __restrict__ W1, const float* __restrict__ b1,
    const float* __restrict__ g1, const float* __restrict__ be1,
    const float* __restrict__ W2, const float* __restrict__ b2,
    const float* __restrict__ g2, const float* __restrict__ be2,
    float* __restrict__ ha, float* __restrict__ hi) {
  const int t = blockIdx.y, ent = blockIdx.z;
  const int cnt = cnts[ent * 3 + t];
  const int base = blockIdx.x * TR;
  if (base >= cnt) return;
  const int nr = (cnt - base < TR) ? (cnt - base) : TR;
  const int j = threadIdx.x;
  const float* feats = ent ? itf : af;
  const int* idx = (ent ? idxI : idxA) + t * BN;
  float* hout = ent ? hi : ha;
  __shared__ __align__(16) float xl[TR * 64];
  __shared__ __align__(16) float z[TR * HDIM];
  __shared__ float red[TR * 8];
  int rows[TR];
  #pragma unroll
  for (int r = 0; r < TR; ++r) {
    int rr = base + r; if (rr > cnt - 1) rr = cnt - 1;
    rows[r] = idx[rr];
  }
  if (j < 64) {
    #pragma unroll
    for (int r = 0; r < TR; ++r)
      xl[r * 64 + j] = (j < MAXD) ? feats[(size_t)rows[r] * MAXD + j] : 0.0f;
  }
  __syncthreads();
  float acc[TR];
  const float bj = b1[t * HDIM + j];
  #pragma unroll
  for (int r = 0; r < TR; ++r) acc[r] = bj;
  matvec_l<MAXD, 64>(W1 + (size_t)t * MAXD * HDIM, xl, acc, j);
  float m[TR], rs[TR];
  row_reduce(red, acc, m, rs, j);
  const float g1j = g1[t * HDIM + j], be1j = be1[t * HDIM + j];
  #pragma unroll
  for (int r = 0; r < TR; ++r)
    z[r * HDIM + j] = fmaxf((acc[r] - m[r]) * rs[r] * g1j + be1j, 0.0f);
  __syncthreads();
  const float b2j = b2[t * HDIM + j];
  #pragma unroll
  for (int r = 0; r < TR; ++r) acc[r] = b2j;
  matvec_l<HDIM, HDIM>(W2 + (size_t)t * HDIM * HDIM, z, acc, j);
  row_reduce(red, acc, m, rs, j);
  const float g2j = g2[t * HDIM + j], be2j = be2[t * HDIM + j];
  #pragma unroll
  for (int r = 0; r < TR; ++r)
    if (r < nr)
      hout[(size_t)rows[r] * HDIM + j] =
          fmaxf((acc[r] - m[r]) * rs[r] * g2j + be2j, 0.0f);
}

__device__ __forceinline__ void hgt_dir_f32(
    const float* __restrict__ Wq, const float* __restrict__ Wk,
    const float* __restrict__ Wv, const float* __restrict__ Wo,
    const float* __restrict__ gg, const float* __restrict__ bb,
    const float* dstl, const float* srcl, float* msg, float* red, int j,
    float res[TR]) {
  float q[TR], kk[TR];
  #pragma unroll
  for (int r = 0; r < TR; ++r) { q[r] = 0.0f; kk[r] = 0.0f; }
  matvec_l<HDIM, HDIM>(Wq, dstl, q, j);
  matvec_l<HDIM, HDIM>(Wk, srcl, kk, j);
  float attn[TR];
  #pragma unroll
  for (int r = 0; r < TR; ++r) {
    float p = q[r] * kk[r];
    #pragma unroll
    for (int o = 32; o; o >>= 1) p += __shfl_xor(p, o);
    attn[r] = 1.0f / (1.0f + expf(-p * 0.125f));
  }
  #pragma unroll
  for (int r = 0; r < TR; ++r) q[r] = 0.0f;
  matvec_l<HDIM, HDIM>(Wv, srcl, q, j);
  __syncthreads();
  #pragma unroll
  for (int r = 0; r < TR; ++r) msg[r * HDIM + j] = attn[r] * q[r];
  __syncthreads();
  float o[TR];
  #pragma unroll
  for (int r = 0; r < TR; ++r) o[r] = 0.0f;
  matvec_l<HDIM, HDIM>(Wo, msg, o, j);
  float u[TR], m[TR], rs[TR];
  #pragma unroll
  for (int r = 0; r < TR; ++r) u[r] = dstl[r * HDIM + j] + o[r];
  row_reduce(red, u, m, rs, j);
  const float gj = gg[j], bj = bb[j];
  #pragma unroll
  for (int r = 0; r < TR; ++r) res[r] = (u[r] - m[r]) * rs[r] * gj + bj;
}

__global__ __launch_bounds__(256) void hop_kernel(
    const float* __restrict__ Wk, const float* __restrict__ Wq,
    const float* __restrict__ Wv, const float* __restrict__ Wout,
    const float* __restrict__ g, const float* __restrict__ b,
    const int* __restrict__ idxC, const int* __restrict__ cnts,
    float* __restrict__ ha, float* __restrict__ hi) {
  const int c = blockIdx.y, a = c / 3, i = c % 3;
  const int cnt = cnts[6 + c];
  const int base = blockIdx.x * TR;
  if (base >= cnt) return;
  const int nr = (cnt - base < TR) ? (cnt - base) : TR;
  const int j = threadIdx.x;
  __shared__ __align__(16) float xa[TR * HDIM];
  __shared__ __align__(16) float xi[TR * HDIM];
  __shared__ __align__(16) float msg[TR * HDIM];
  __shared__ float red[TR * 8];
  int rows[TR];
  #pragma unroll
  for (int r = 0; r < TR; ++r) {
    int rr = base + r; if (rr > cnt - 1) rr = cnt - 1;
    rows[r] = idxC[c * BN + rr];
  }
  #pragma unroll
  for (int r = 0; r < TR; ++r) {
    xa[r * HDIM + j] = ha[(size_t)rows[r] * HDIM + j];
    xi[r * HDIM + j] = hi[(size_t)rows[r] * HDIM + j];
  }
  __syncthreads();
  const int e1 = i * 3 + a, e2 = a * 3 + i;
  float res1[TR], res2[TR];
  hgt_dir_f32(Wq + (size_t)e1 * HDIM * HDIM, Wk + (size_t)e1 * HDIM * HDIM,
              Wv + (size_t)e1 * HDIM * HDIM, Wout + (size_t)a * HDIM * HDIM,
              g + a * HDIM, b + a * HDIM, xa, xi, msg, red, j, res1);
  hgt_dir_f32(Wq + (size_t)e2 * HDIM * HDIM, Wk + (size_t)e2 * HDIM * HDIM,
              Wv + (size_t)e2 * HDIM * HDIM, Wout + (size_t)i * HDIM * HDIM,
              g + i * HDIM, b + i * HDIM, xi, xa, msg, red, j, res2);
  #pragma unroll
  for (int r = 0; r < TR; ++r)
    if (r < nr) {
      ha[(size_t)rows[r] * HDIM + j] = res1[r];
      hi[(size_t)rows[r] * HDIM + j] = res2[r];
    }
}

__global__ __launch_bounds__(256) void out_kernel(
    const float* __restrict__ W, const float* __restrict__ bb,
    const float* __restrict__ g, const float* __restrict__ be,
    float* __restrict__ out) {
  const int ent = blockIdx.y;
  const int base = blockIdx.x * TR;
  const int j = threadIdx.x;
  float* hsrc = out + (size_t)ent * BN * HDIM;
  __shared__ __align__(16) float xl[TR * HDIM];
  __shared__ float red[TR * 8];
  #pragma unroll
  for (int r = 0; r < TR; ++r)
    xl[r * HDIM + j] = hsrc[(size_t)(base + r) * HDIM + j];
  __syncthreads();
  float acc[TR];
  const float bj = bb[j];
  #pragma unroll
  for (int r = 0; r < TR; ++r) acc[r] = bj;
  matvec_l<HDIM, HDIM>(W, xl, acc, j);
  float m[TR], rs[TR];
  row_reduce(red, acc, m, rs, j);
  const float gj = g[j], bej = be[j];
  float y[TR];
  #pragma unroll
  for (int r = 0; r < TR; ++r) y[r] = (acc[r] - m[r]) * rs[r] * gj + bej;
  const int lane = j & 63, wv = j >> 6;
  __syncthreads();
  #pragma unroll
  for (int r = 0; r < TR; ++r) {
    float p = y[r] * y[r];
    #pragma unroll
    for (int o = 32; o; o >>= 1) p += __shfl_xor(p, o);
    if (lane == 0) red[r * 4 + wv] = p;
  }
  __syncthreads();
  #pragma unroll
  for (int r = 0; r < TR; ++r) {
    float ss = red[r * 4] + red[r * 4 + 1] + red[r * 4 + 2] + red[r * 4 + 3];
    float inv = 1.0f / fmaxf(sqrtf(ss), 1e-12f);
    hsrc[(size_t)(base + r) * HDIM + j] = y[r] * inv;
  }
}

// ---------------- launch ----------------

extern "C" void kernel_launch(void* const* d_in, const int* in_sizes, int n_in,
                              void* d_out, int out_size, void* d_ws,
                              size_t ws_size, hipStream_t stream) {
  const float* af   = (const float*)d_in[0];
  const float* itf  = (const float*)d_in[1];
  const int*   atid = (const int*)d_in[2];
  const int*   itid = (const int*)d_in[3];
  const float* eW1  = (const float*)d_in[4];
  const float* eb1  = (const float*)d_in[5];
  const float* eg1  = (const float*)d_in[6];
  const float* ebe1 = (const float*)d_in[7];
  const float* eW2  = (const float*)d_in[8];
  const float* eb2  = (const float*)d_in[9];
  const float* eg2  = (const float*)d_in[10];
  const float* ebe2 = (const float*)d_in[11];
  const float* hWk  = (const float*)d_in[12];
  const float* hWq  = (const float*)d_in[13];
  const float* hWv  = (const float*)d_in[14];
  const float* hWo  = (const float*)d_in[15];
  const float* hg   = (const float*)d_in[16];
  const float* hb   = (const float*)d_in[17];
  const float* oW   = (const float*)d_in[18];
  const float* ob   = (const float*)d_in[19];
  const float* og   = (const float*)d_in[20];
  const float* obe  = (const float*)d_in[21];

  float* out = (float*)d_out;
  float* ha = out;
  float* hi = out + (size_t)BN * HDIM;

  int* cnts = (int*)d_ws;       // [16]
  int* idxA = cnts + 16;        // [3][BN]
  int* idxI = idxA + 3 * BN;    // [3][BN]
  int* idxC = idxI + 3 * BN;    // [9][BN]
  unsigned short* pW1 = (unsigned short*)(idxC + 9 * BN);  // 3*16384
  unsigned short* pW2 = pW1 + 3 * 16384;                   // 3*65536
  unsigned short* pWk = pW2 + 3 * 65536;                   // 18*65536
  unsigned short* pWq = pWk + 18 * 65536;
  unsigned short* pWv = pWq + 18 * 65536;
  unsigned short* pWo = pWv + 18 * 65536;                  // 6*65536
  unsigned short* pOW = pWo + 6 * 65536;                   // 1*65536
  const size_t ws_need = (size_t)(16 + 15 * BN) * 4 +
                         ((size_t)3 * 16384 + (size_t)64 * 65536) * 2;
  const bool use_mfma = ws_size >= ws_need;

  hipMemsetAsync(cnts, 0, 16 * sizeof(int), stream);
  bucket_kernel<<<BN / 256, 256, 0, stream>>>(atid, itid, cnts, idxA, idxI, idxC);

  if (use_mfma) {
    wpack_kernel<<<3 * 16384 / 256, 256, 0, stream>>>(eW1, pW1, 3, 2, 60);
    wpack_kernel<<<3 * 65536 / 256, 256, 0, stream>>>(eW2, pW2, 3, 8, 256);
    wpack_kernel<<<18 * 65536 / 256, 256, 0, stream>>>(hWk, pWk, 18, 8, 256);
    wpack_kernel<<<18 * 65536 / 256, 256, 0, stream>>>(hWq, pWq, 18, 8, 256);
    wpack_kernel<<<18 * 65536 / 256, 256, 0, stream>>>(hWv, pWv, 18, 8, 256);
    wpack_kernel<<<6 * 65536 / 256, 256, 0, stream>>>(hWo, pWo, 6, 8, 256);
    wpack_kernel<<<65536 / 256, 256, 0, stream>>>(oW, pOW, 1, 8, 256);

    enc_mfma_kernel<<<dim3(BN / 32, 3, 2), 256, 0, stream>>>(
        af, itf, idxA, idxI, cnts, pW1, pW2,
        eb1, eg1, ebe1, eb2, eg2, ebe2, ha, hi);
    for (int L = 0; L < 2; ++L) {
      hop_mfma_kernel<<<dim3(BN / 32, 9), 256, 0, stream>>>(
          pWk + (size_t)L * 9 * 65536, pWq + (size_t)L * 9 * 65536,
          pWv + (size_t)L * 9 * 65536, pWo + (size_t)L * 3 * 65536,
          hg + L * 3 * HDIM, hb + L * 3 * HDIM, idxC, cnts, ha, hi);
    }
    out_mfma_kernel<<<dim3(BN / 32, 2), 256, 0, stream>>>(pOW, ob, og, obe, out);
  } else {
    enc_kernel<<<dim3((BN + TR - 1) / TR, 3, 2), 256, 0, stream>>>(
        af, itf, idxA, idxI, cnts, eW1, eb1, eg1, ebe1, eW2, eb2, eg2, ebe2,
        ha, hi);
    for (int L = 0; L < 2; ++L) {
      hop_kernel<<<dim3((BN + TR - 1) / TR, 9), 256, 0, stream>>>(
          hWk + (size_t)L * 9 * HDIM * HDIM, hWq + (size_t)L * 9 * HDIM * HDIM,
          hWv + (size_t)L * 9 * HDIM * HDIM, hWo + (size_t)L * 3 * HDIM * HDIM,
          hg + L * 3 * HDIM, hb + L * 3 * HDIM, idxC, cnts, ha, hi);
    }
    out_kernel<<<dim3(BN / TR, 2), 256, 0, stream>>>(oW, ob, og, obe, out);
  }
}